// Round 1
// baseline (3284.015 us; speedup 1.0000x reference)
//
#include <hip/hip_runtime.h>
#include <hip/hip_bf16.h>

#define TT 20
#define BB 64
#define SS 64
#define HH 512
#define EE 512
#define VV 32000

typedef __bf16 bf16x8 __attribute__((ext_vector_type(8)));
typedef float f32x4 __attribute__((ext_vector_type(4)));

__device__ __forceinline__ void gload_lds16(const __hip_bfloat16* g, __hip_bfloat16* l) {
    __builtin_amdgcn_global_load_lds((const __attribute__((address_space(1))) void*)g,
                                     (__attribute__((address_space(3))) void*)l, 16, 0, 0);
}

__device__ __forceinline__ float sigmf(float x) { return 1.f / (1.f + __expf(-x)); }

// ---------------- elementwise helpers ----------------

__global__ __launch_bounds__(256) void f2bf_kernel(const float* __restrict__ in,
                                                   __hip_bfloat16* __restrict__ out, int n) {
    int i = blockIdx.x * 256 + threadIdx.x;
    if (i < n) out[i] = __float2bfloat16(in[i]);
}

// out[k*512 + j] = in[j*512 + k]  (fp32 -> bf16, k-major transpose of a 512x512 block)
__global__ __launch_bounds__(256) void transpose512_kernel(const float* __restrict__ in,
                                                           __hip_bfloat16* __restrict__ out) {
    int i = blockIdx.x * 256 + threadIdx.x;  // 262144 total
    int j = i >> 9, k = i & 511;
    out[(size_t)k * 512 + j] = __float2bfloat16(in[i]);
}

__global__ __launch_bounds__(256) void zero_h_kernel(float* __restrict__ hf,
                                                     __hip_bfloat16* __restrict__ hb) {
    int i = blockIdx.x * 256 + threadIdx.x;  // 2*3*64*512 threads
    hb[i] = __float2bfloat16(0.f);
    if (i < 3 * 64 * 512) hf[i] = 0.f;
}

// xs[t][b][e] = embed_table[captions[b][t]][e], stored bf16 at (t*64+b)*512+e
__global__ __launch_bounds__(256) void gather_emb_kernel(const float* __restrict__ tab,
                                                         const int* __restrict__ cap,
                                                         __hip_bfloat16* __restrict__ out) {
    int i = blockIdx.x * 256 + threadIdx.x;  // T*B*E total
    int e = i & (EE - 1);
    int tb = i >> 9;
    int t = tb >> 6;
    int b = tb & 63;
    int tok = cap[b * TT + t];
    out[i] = __float2bfloat16(tab[(size_t)tok * EE + e]);
}

// ---------------- gemm128: C[M,N] = A[M,K] @ B[N,K]^T (+bias), fp32 out ----------------
// m97 structure: 128x128 block tile, BK=32, LDS staged via global_load_lds width 16,
// 4 waves (2x2), each wave 64x64 = 4x4 frags of 16x16x32 bf16 MFMA.
// Requires M%128==0, N%128==0, K%32==0.

__global__ __launch_bounds__(256) void gemm128_kernel(
    const __hip_bfloat16* __restrict__ A,
    const __hip_bfloat16* __restrict__ Bm,
    const float* __restrict__ bias,
    float* __restrict__ C,
    int K, int N)
{
    __shared__ __align__(16) __hip_bfloat16 As[128 * 32];
    __shared__ __align__(16) __hip_bfloat16 Bs[128 * 32];

    int m0 = blockIdx.x * 128, n0 = blockIdx.y * 128;
    int tid = threadIdx.x;
    int wave = tid >> 6, lane = tid & 63;
    int wm = wave & 1, wn = wave >> 1;
    int row16 = lane & 15, quad = lane >> 4;

    // staging: chunk c (8 elems each) of the 128x32 tile; pass0 chunks = tid, pass1 = 256+tid
    int r0 = tid >> 2, cc = (tid & 3) * 8;
    int r1 = 64 + r0;
    const __hip_bfloat16* gA0 = A  + (size_t)(m0 + r0) * K + cc;
    const __hip_bfloat16* gA1 = A  + (size_t)(m0 + r1) * K + cc;
    const __hip_bfloat16* gB0 = Bm + (size_t)(n0 + r0) * K + cc;
    const __hip_bfloat16* gB1 = Bm + (size_t)(n0 + r1) * K + cc;
    __hip_bfloat16* lA0 = As + (size_t)(wave * 64) * 8;
    __hip_bfloat16* lA1 = As + (size_t)(256 + wave * 64) * 8;
    __hip_bfloat16* lB0 = Bs + (size_t)(wave * 64) * 8;
    __hip_bfloat16* lB1 = Bs + (size_t)(256 + wave * 64) * 8;

    const __hip_bfloat16* ra = As + (size_t)(wm * 64 + row16) * 32 + quad * 8;
    const __hip_bfloat16* rb = Bs + (size_t)(wn * 64 + row16) * 32 + quad * 8;

    f32x4 acc[4][4] = {};

    for (int k = 0; k < K; k += 32) {
        gload_lds16(gA0 + k, lA0);
        gload_lds16(gA1 + k, lA1);
        gload_lds16(gB0 + k, lB0);
        gload_lds16(gB1 + k, lB1);
        __syncthreads();
        bf16x8 af[4], bfr[4];
#pragma unroll
        for (int mt = 0; mt < 4; ++mt)
            af[mt] = *reinterpret_cast<const bf16x8*>(ra + mt * 16 * 32);
#pragma unroll
        for (int nt = 0; nt < 4; ++nt)
            bfr[nt] = *reinterpret_cast<const bf16x8*>(rb + nt * 16 * 32);
#pragma unroll
        for (int mt = 0; mt < 4; ++mt)
#pragma unroll
            for (int nt = 0; nt < 4; ++nt)
                acc[mt][nt] = __builtin_amdgcn_mfma_f32_16x16x32_bf16(af[mt], bfr[nt], acc[mt][nt], 0, 0, 0);
        __syncthreads();
    }

#pragma unroll
    for (int mt = 0; mt < 4; ++mt)
#pragma unroll
        for (int nt = 0; nt < 4; ++nt) {
            int col = n0 + wn * 64 + nt * 16 + row16;
            float bv = bias ? bias[col] : 0.f;
#pragma unroll
            for (int r = 0; r < 4; ++r) {
                int row = m0 + wm * 64 + mt * 16 + quad * 4 + r;
                C[(size_t)row * N + col] = acc[mt][nt][r] + bv;
            }
        }
}

// ---------------- fused GRU layer ----------------
// Grid: 8 blocks, each owns a 64-col slice of the 64x512 h state.
// GI_pre != null (layer 0): i-gates = GI_pre (precomputed x@Wih^T, no bias).
// Else: computes GI = x_bf @ Wih^T on the fly. Always computes GH = h_bf @ Whh^T.
// r/z gates accumulate GI+GH in one MFMA acc; n keeps i_n / h_n separate.
// hb ping-pong: h_bf (read, full rows) is last step's buffer; hb_out is the other.
// hf is read only at positions this thread writes -> single-buffered in-place.

__global__ __launch_bounds__(256) void gru_fused_kernel(
    const __hip_bfloat16* __restrict__ x_bf,
    const float* __restrict__ GI_pre,
    const __hip_bfloat16* __restrict__ h_bf,
    const float* h_f,
    const __hip_bfloat16* __restrict__ Wih,
    const __hip_bfloat16* __restrict__ Whh,
    const float* __restrict__ bih, const float* __restrict__ bhh,
    float* hf_out, __hip_bfloat16* __restrict__ hb_out)
{
    int j0 = blockIdx.x * 64;
    int wave = threadIdx.x >> 6, lane = threadIdx.x & 63;
    int wm = wave & 1, wn = wave >> 1;
    int row16 = lane & 15, quad = lane >> 4;

    size_t aoff = (size_t)(wm * 32 + row16) * 512 + quad * 8;
    int bcol = j0 + wn * 32 + row16;
    size_t boff = (size_t)bcol * 512 + quad * 8;

    f32x4 aR[2][2] = {}, aZ[2][2] = {}, aIN[2][2] = {}, aHN[2][2] = {};

    auto tile = [&](const __hip_bfloat16* Ab, const __hip_bfloat16* Wb, f32x4 (&acc)[2][2]) {
        const __hip_bfloat16* a0 = Ab + aoff;
        const __hip_bfloat16* a1 = a0 + 16 * 512;
        const __hip_bfloat16* b0 = Wb + boff;
        const __hip_bfloat16* b1 = b0 + 16 * 512;
#pragma unroll
        for (int k = 0; k < 512; k += 32) {
            bf16x8 av0 = *reinterpret_cast<const bf16x8*>(a0 + k);
            bf16x8 av1 = *reinterpret_cast<const bf16x8*>(a1 + k);
            bf16x8 bv0 = *reinterpret_cast<const bf16x8*>(b0 + k);
            bf16x8 bv1 = *reinterpret_cast<const bf16x8*>(b1 + k);
            acc[0][0] = __builtin_amdgcn_mfma_f32_16x16x32_bf16(av0, bv0, acc[0][0], 0, 0, 0);
            acc[0][1] = __builtin_amdgcn_mfma_f32_16x16x32_bf16(av0, bv1, acc[0][1], 0, 0, 0);
            acc[1][0] = __builtin_amdgcn_mfma_f32_16x16x32_bf16(av1, bv0, acc[1][0], 0, 0, 0);
            acc[1][1] = __builtin_amdgcn_mfma_f32_16x16x32_bf16(av1, bv1, acc[1][1], 0, 0, 0);
        }
    };

    tile(h_bf, Whh, aR);
    tile(h_bf, Whh + (size_t)512 * 512, aZ);
    tile(h_bf, Whh + (size_t)1024 * 512, aHN);
    if (!GI_pre) {
        tile(x_bf, Wih, aR);
        tile(x_bf, Wih + (size_t)512 * 512, aZ);
        tile(x_bf, Wih + (size_t)1024 * 512, aIN);
    }

#pragma unroll
    for (int mt = 0; mt < 2; ++mt)
#pragma unroll
        for (int nt = 0; nt < 2; ++nt) {
            int col = j0 + wn * 32 + nt * 16 + row16;
            float b_r  = bih[col] + bhh[col];
            float b_z  = bih[512 + col] + bhh[512 + col];
            float bi_n = bih[1024 + col];
            float bh_n = bhh[1024 + col];
#pragma unroll
            for (int r = 0; r < 4; ++r) {
                int row = wm * 32 + mt * 16 + quad * 4 + r;
                float vr = aR[mt][nt][r], vz = aZ[mt][nt][r];
                float vin = aIN[mt][nt][r], vhn = aHN[mt][nt][r];
                if (GI_pre) {
                    const float* gp = GI_pre + (size_t)row * 1536 + col;
                    vr += gp[0]; vz += gp[512]; vin += gp[1024];
                }
                float rr = sigmf(vr + b_r);
                float zz = sigmf(vz + b_z);
                float nn = tanhf(vin + bi_n + rr * (vhn + bh_n));
                size_t o = (size_t)row * 512 + col;
                float hnew = (1.f - zz) * nn + zz * h_f[o];
                hf_out[o] = hnew;
                hb_out[o] = __float2bfloat16(hnew);
            }
        }
}

// ---------------- fused q-proj + attention + out-proj ----------------
// One block per batch element b: 512 threads = 8 waves (one per head).
// Phase 1: q[j] = bq[j] + h2[b,:] . WqT[:,j]   (WqT k-major bf16, coalesced)
// Phase 2: per-head scores/softmax/ctx (lane = kv position / head dim)
// Phase 3: AO[b*T+t, j] = bo[j] + ctx[b,:] . WoT[:,j]  (bf16 out)

__global__ __launch_bounds__(512) void attn_fused_kernel(
    const float* __restrict__ h2,
    const float* __restrict__ KV,
    const __hip_bfloat16* __restrict__ WqT,
    const float* __restrict__ bq,
    const __hip_bfloat16* __restrict__ WoT,
    const float* __restrict__ bo,
    __hip_bfloat16* __restrict__ AO,
    int t)
{
    int b = blockIdx.x;
    int tid = threadIdx.x;
    __shared__ float qs[512];
    __shared__ float pl[512];
    __shared__ float cs[512];

    const float* hrow = h2 + (size_t)b * 512;
    float qacc = bq[tid];
#pragma unroll 8
    for (int k = 0; k < 512; ++k)
        qacc += hrow[k] * __bfloat162float(WqT[(size_t)k * 512 + tid]);
    qs[tid] = qacc;
    __syncthreads();

    int nh = tid >> 6, lane = tid & 63;
    const float* qh = qs + nh * 64;
    const float* kr = KV + (size_t)(b * 64 + lane) * 1024 + nh * 64;
    float sc = 0.f;
#pragma unroll
    for (int d = 0; d < 64; ++d) sc += qh[d] * kr[d];
    sc *= 0.125f;  // 1/sqrt(64)
    float m = sc;
    for (int off = 32; off; off >>= 1) m = fmaxf(m, __shfl_xor(m, off, 64));
    float e = __expf(sc - m);
    float s = e;
    for (int off = 32; off; off >>= 1) s += __shfl_xor(s, off, 64);
    pl[tid] = e / s;
    __syncthreads();

    float cacc = 0.f;
    const float* ph = pl + nh * 64;
    const float* vb = KV + (size_t)(b * 64) * 1024 + 512 + nh * 64 + lane;
#pragma unroll
    for (int si = 0; si < 64; ++si) cacc += ph[si] * vb[(size_t)si * 1024];
    cs[tid] = cacc;
    __syncthreads();

    float ao = bo[tid];
#pragma unroll 8
    for (int k = 0; k < 512; ++k)
        ao += cs[k] * __bfloat162float(WoT[(size_t)k * 512 + tid]);
    AO[((size_t)b * TT + t) * 512 + tid] = __float2bfloat16(ao);
}

// ---------------- host ----------------

extern "C" void kernel_launch(void* const* d_in, const int* in_sizes, int n_in,
                              void* d_out, int out_size, void* d_ws, size_t ws_size,
                              hipStream_t stream) {
    const float* enc        = (const float*)d_in[0];
    const int*   cap        = (const int*)d_in[1];
    const float* emb_tab    = (const float*)d_in[2];
    const float* w_ih       = (const float*)d_in[3];
    const float* w_hh       = (const float*)d_in[4];
    const float* b_ih       = (const float*)d_in[5];
    const float* b_hh       = (const float*)d_in[6];
    const float* in_proj_w  = (const float*)d_in[7];
    const float* in_proj_b  = (const float*)d_in[8];
    const float* out_proj_w = (const float*)d_in[9];
    const float* out_proj_b = (const float*)d_in[10];
    const float* fc_w       = (const float*)d_in[11];
    const float* fc_b       = (const float*)d_in[12];
    float* out = (float*)d_out;

    char* p = (char*)d_ws;
    auto alloc = [&](size_t bytes) {
        char* r = p;
        p += (bytes + 255) & ~(size_t)255;
        return r;
    };
    __hip_bfloat16* fcw_bf  = (__hip_bfloat16*)alloc((size_t)VV * HH * 2);
    __hip_bfloat16* enc_bf  = (__hip_bfloat16*)alloc((size_t)BB * SS * HH * 2);
    __hip_bfloat16* inp_bf  = (__hip_bfloat16*)alloc((size_t)1536 * 512 * 2);
    __hip_bfloat16* wih_bf  = (__hip_bfloat16*)alloc((size_t)3 * 1536 * 512 * 2);
    __hip_bfloat16* whh_bf  = (__hip_bfloat16*)alloc((size_t)3 * 1536 * 512 * 2);
    __hip_bfloat16* xemb_bf = (__hip_bfloat16*)alloc((size_t)TT * BB * EE * 2);
    float* KV   = (float*)alloc((size_t)4096 * 1024 * 4);
    float* GI0  = (float*)alloc((size_t)1280 * 1536 * 4);
    __hip_bfloat16* WqT = (__hip_bfloat16*)alloc((size_t)512 * 512 * 2);
    __hip_bfloat16* WoT = (__hip_bfloat16*)alloc((size_t)512 * 512 * 2);
    float* hf = (float*)alloc((size_t)3 * 64 * 512 * 4);           // single-buffered fp32 h
    __hip_bfloat16* hb = (__hip_bfloat16*)alloc((size_t)2 * 3 * 64 * 512 * 2);  // ping-pong bf16 h
    __hip_bfloat16* AO = (__hip_bfloat16*)alloc((size_t)1280 * 512 * 2);

    auto cvt = [&](const float* src, __hip_bfloat16* dst, int n) {
        f2bf_kernel<<<(n + 255) / 256, 256, 0, stream>>>(src, dst, n);
    };
    cvt(fc_w, fcw_bf, VV * HH);
    cvt(enc, enc_bf, BB * SS * HH);
    cvt(in_proj_w, inp_bf, 1536 * 512);
    cvt(w_ih, wih_bf, 3 * 1536 * 512);
    cvt(w_hh, whh_bf, 3 * 1536 * 512);
    transpose512_kernel<<<1024, 256, 0, stream>>>(in_proj_w, WqT);   // Wq = first 512 rows
    transpose512_kernel<<<1024, 256, 0, stream>>>(out_proj_w, WoT);
    gather_emb_kernel<<<(TT * BB * EE) / 256, 256, 0, stream>>>(emb_tab, cap, xemb_bf);
    zero_h_kernel<<<(2 * 3 * 64 * 512) / 256, 256, 0, stream>>>(hf, hb);

    // KV = enc @ [Wk;Wv]^T + [bk;bv]   (4096 x 1024, K=512)
    gemm128_kernel<<<dim3(32, 8), 256, 0, stream>>>(
        enc_bf, inp_bf + 512 * 512, in_proj_b + 512, KV, 512, 1024);

    // GI0 = xemb @ Wih0^T   (1280 x 1536, no bias)
    gemm128_kernel<<<dim3(10, 12), 256, 0, stream>>>(
        xemb_bf, wih_bf, nullptr, GI0, 512, 1536);

    const size_t HS = (size_t)64 * 512;
    auto hbp = [&](int buf, int l) { return hb + ((size_t)buf * 3 + l) * HS; };

    for (int t = 0; t < TT; ++t) {
        int cur = t & 1, nxt = cur ^ 1;
        // layer 0 (GI precomputed)
        gru_fused_kernel<<<8, 256, 0, stream>>>(
            nullptr, GI0 + (size_t)t * 64 * 1536, hbp(cur, 0), hf,
            nullptr, whh_bf, b_ih, b_hh, hf, hbp(nxt, 0));
        // layer 1
        gru_fused_kernel<<<8, 256, 0, stream>>>(
            hbp(nxt, 0), nullptr, hbp(cur, 1), hf + HS,
            wih_bf + (size_t)1536 * 512, whh_bf + (size_t)1536 * 512,
            b_ih + 1536, b_hh + 1536, hf + HS, hbp(nxt, 1));
        // layer 2
        gru_fused_kernel<<<8, 256, 0, stream>>>(
            hbp(nxt, 1), nullptr, hbp(cur, 2), hf + 2 * HS,
            wih_bf + (size_t)2 * 1536 * 512, whh_bf + (size_t)2 * 1536 * 512,
            b_ih + 2 * 1536, b_hh + 2 * 1536, hf + 2 * HS, hbp(nxt, 2));
        // q-proj + attention + out-proj
        attn_fused_kernel<<<64, 512, 0, stream>>>(
            hf + 2 * HS, KV, WqT, in_proj_b, WoT, out_proj_b, AO, t);
    }

    // logits = AO @ fc_w^T + fc_b   (1280 x 32000) -> d_out (B,T,V)
    gemm128_kernel<<<dim3(10, 250), 256, 0, stream>>>(
        AO, fcw_bf, fc_b, out, 512, VV);
}

// Round 2
// 2484.219 us; speedup vs baseline: 1.3220x; 1.3220x over previous
//
#include <hip/hip_runtime.h>
#include <hip/hip_bf16.h>

#define TT 20
#define BB 64
#define SS 64
#define HH 512
#define EE 512
#define VV 32000
#define NBLK 32

typedef __bf16 bf16x8 __attribute__((ext_vector_type(8)));
typedef float f32x4 __attribute__((ext_vector_type(4)));

__device__ __forceinline__ void gload_lds16(const __hip_bfloat16* g, __hip_bfloat16* l) {
    __builtin_amdgcn_global_load_lds((const __attribute__((address_space(1))) void*)g,
                                     (__attribute__((address_space(3))) void*)l, 16, 0, 0);
}

__device__ __forceinline__ float sigmf(float x) { return 1.f / (1.f + __expf(-x)); }

// ---------------- elementwise helpers ----------------

__global__ __launch_bounds__(256) void f2bf_kernel(const float* __restrict__ in,
                                                   __hip_bfloat16* __restrict__ out, int n) {
    int i = blockIdx.x * 256 + threadIdx.x;
    if (i < n) out[i] = __float2bfloat16(in[i]);
}

// xs[t][b][e] = embed_table[captions[b][t]][e], stored bf16 at (t*64+b)*512+e
__global__ __launch_bounds__(256) void gather_emb_kernel(const float* __restrict__ tab,
                                                         const int* __restrict__ cap,
                                                         __hip_bfloat16* __restrict__ out) {
    int i = blockIdx.x * 256 + threadIdx.x;  // T*B*E total
    int e = i & (EE - 1);
    int tb = i >> 9;
    int t = tb >> 6;
    int b = tb & 63;
    int tok = cap[b * TT + t];
    out[i] = __float2bfloat16(tab[(size_t)tok * EE + e]);
}

// zero h state (buffer 0 of ping-pong) + barrier counters
__global__ __launch_bounds__(256) void init_kernel(float* __restrict__ hf,
                                                   __hip_bfloat16* __restrict__ hb,
                                                   int* __restrict__ bar) {
    int i = blockIdx.x * 256 + threadIdx.x;  // 3*64*512 threads
    hf[i] = 0.f;
    hb[i] = __float2bfloat16(0.f);
    if (i < 2) bar[i] = 0;
}

// ---------------- gemm128: C[M,N] = A[M,K] @ B[N,K]^T (+bias), fp32 out ----------------
// m97 structure: 128x128 tile, BK=32, global_load_lds width 16, 4 waves, 4x4 frags.

__global__ __launch_bounds__(256) void gemm128_kernel(
    const __hip_bfloat16* __restrict__ A,
    const __hip_bfloat16* __restrict__ Bm,
    const float* __restrict__ bias,
    float* __restrict__ C,
    int K, int N)
{
    __shared__ __align__(16) __hip_bfloat16 As[128 * 32];
    __shared__ __align__(16) __hip_bfloat16 Bs[128 * 32];

    int m0 = blockIdx.x * 128, n0 = blockIdx.y * 128;
    int tid = threadIdx.x;
    int wave = tid >> 6, lane = tid & 63;
    int wm = wave & 1, wn = wave >> 1;
    int row16 = lane & 15, quad = lane >> 4;

    int r0 = tid >> 2, cc = (tid & 3) * 8;
    int r1 = 64 + r0;
    const __hip_bfloat16* gA0 = A  + (size_t)(m0 + r0) * K + cc;
    const __hip_bfloat16* gA1 = A  + (size_t)(m0 + r1) * K + cc;
    const __hip_bfloat16* gB0 = Bm + (size_t)(n0 + r0) * K + cc;
    const __hip_bfloat16* gB1 = Bm + (size_t)(n0 + r1) * K + cc;
    __hip_bfloat16* lA0 = As + (size_t)(wave * 64) * 8;
    __hip_bfloat16* lA1 = As + (size_t)(256 + wave * 64) * 8;
    __hip_bfloat16* lB0 = Bs + (size_t)(wave * 64) * 8;
    __hip_bfloat16* lB1 = Bs + (size_t)(256 + wave * 64) * 8;

    const __hip_bfloat16* ra = As + (size_t)(wm * 64 + row16) * 32 + quad * 8;
    const __hip_bfloat16* rb = Bs + (size_t)(wn * 64 + row16) * 32 + quad * 8;

    f32x4 acc[4][4] = {};

    for (int k = 0; k < K; k += 32) {
        gload_lds16(gA0 + k, lA0);
        gload_lds16(gA1 + k, lA1);
        gload_lds16(gB0 + k, lB0);
        gload_lds16(gB1 + k, lB1);
        __syncthreads();
        bf16x8 af[4], bfr[4];
#pragma unroll
        for (int mt = 0; mt < 4; ++mt)
            af[mt] = *reinterpret_cast<const bf16x8*>(ra + mt * 16 * 32);
#pragma unroll
        for (int nt = 0; nt < 4; ++nt)
            bfr[nt] = *reinterpret_cast<const bf16x8*>(rb + nt * 16 * 32);
#pragma unroll
        for (int mt = 0; mt < 4; ++mt)
#pragma unroll
            for (int nt = 0; nt < 4; ++nt)
                acc[mt][nt] = __builtin_amdgcn_mfma_f32_16x16x32_bf16(af[mt], bfr[nt], acc[mt][nt], 0, 0, 0);
        __syncthreads();
    }

#pragma unroll
    for (int mt = 0; mt < 4; ++mt)
#pragma unroll
        for (int nt = 0; nt < 4; ++nt) {
            int col = n0 + wn * 64 + nt * 16 + row16;
            float bv = bias ? bias[col] : 0.f;
#pragma unroll
            for (int r = 0; r < 4; ++r) {
                int row = m0 + wm * 64 + mt * 16 + quad * 4 + r;
                C[(size_t)row * N + col] = acc[mt][nt][r] + bv;
            }
        }
}

// ---------------- persistent recurrence kernel ----------------
// Grid: 32 blocks x 512 threads (8 waves), trivially co-resident on 256 CUs.
// Block j owns h-column slice [j*16, j*16+16). Manual device-scope grid barrier.
// Per step: [GRU l0] bar [GRU l1] bar [GRU l2] bar [q-proj] bar [attn] bar [AO-proj].
// h state ping-pongs by t parity (read cur, write nxt) to avoid cross-block WAR.

__global__ __launch_bounds__(512) void recurrence_kernel(
    const float* __restrict__ GI0,            // [1280][1536] = xemb @ Wih0^T
    const __hip_bfloat16* __restrict__ wih,   // [3][1536][512]
    const __hip_bfloat16* __restrict__ whh,   // [3][1536][512]
    const float* __restrict__ bih,            // [3][1536]
    const float* __restrict__ bhh,
    const __hip_bfloat16* __restrict__ wq,    // [512][512] (in_proj rows 0..511)
    const float* __restrict__ bq,             // in_proj_b[0..512)
    const __hip_bfloat16* __restrict__ wo,    // [512][512]
    const float* __restrict__ bo,
    const float* __restrict__ KV,             // [4096][1024] fp32 (K | V)
    float* __restrict__ hf,                   // [2][3][64][512] fp32
    __hip_bfloat16* __restrict__ hb,          // [2][3][64][512] bf16
    float* __restrict__ qbuf,                 // [64][512]
    __hip_bfloat16* __restrict__ ctxb,        // [64][512]
    __hip_bfloat16* __restrict__ AO,          // [1280][512] (row = b*T + t)
    int* __restrict__ bar)                    // [0]=cnt, [1]=gen
{
    __shared__ __align__(16) float parts[12][32][16];

    const int tid = threadIdx.x;
    const int w = tid >> 6, lane = tid & 63;
    const int row16 = lane & 15, quad = lane >> 4;
    const int blk = blockIdx.x;
    const int c0 = blk * 16;
    const size_t HS = (size_t)64 * 512;

    int lgen = 0;
    auto gridbar = [&]() {
        __syncthreads();
        if (tid == 0) {
            __threadfence();
            lgen++;
            int v = __hip_atomic_fetch_add(&bar[0], 1, __ATOMIC_ACQ_REL, __HIP_MEMORY_SCOPE_AGENT);
            if (v == NBLK - 1) {
                __hip_atomic_store(&bar[0], 0, __ATOMIC_RELAXED, __HIP_MEMORY_SCOPE_AGENT);
                __hip_atomic_store(&bar[1], lgen, __ATOMIC_RELEASE, __HIP_MEMORY_SCOPE_AGENT);
            } else {
                while (__hip_atomic_load(&bar[1], __ATOMIC_ACQUIRE, __HIP_MEMORY_SCOPE_AGENT) < lgen)
                    __builtin_amdgcn_s_sleep(1);
            }
            __threadfence();
        }
        __syncthreads();
    };

    // wave-tile GEMM: out 32 rows x 16 cols, A row-stride 512, W row-stride 512
    auto wtile = [&](const __hip_bfloat16* Ab, const __hip_bfloat16* Wb, int ksteps, f32x4* acc) {
        const __hip_bfloat16* ap0 = Ab + (size_t)row16 * 512 + quad * 8;
        const __hip_bfloat16* ap1 = ap0 + (size_t)16 * 512;
        const __hip_bfloat16* bp  = Wb + (size_t)row16 * 512 + quad * 8;
#pragma unroll
        for (int ks = 0; ks < ksteps; ++ks) {
            bf16x8 a0 = *reinterpret_cast<const bf16x8*>(ap0 + ks * 32);
            bf16x8 a1 = *reinterpret_cast<const bf16x8*>(ap1 + ks * 32);
            bf16x8 bv = *reinterpret_cast<const bf16x8*>(bp + ks * 32);
            acc[0] = __builtin_amdgcn_mfma_f32_16x16x32_bf16(a0, bv, acc[0], 0, 0, 0);
            acc[1] = __builtin_amdgcn_mfma_f32_16x16x32_bf16(a1, bv, acc[1], 0, 0, 0);
        }
    };

    auto store_parts = [&](int jid, const f32x4* acc) {
#pragma unroll
        for (int mf = 0; mf < 2; ++mf)
#pragma unroll
            for (int r = 0; r < 4; ++r)
                parts[jid][mf * 16 + quad * 4 + r][row16] = acc[mf][r];
    };

    auto gru_stage = [&](int l, int t, int cur) {
        int nxt = cur ^ 1;
        const __hip_bfloat16* hown = hb + (size_t)(cur * 3 + l) * HS;
        const __hip_bfloat16* xin  = l ? hb + (size_t)(nxt * 3 + (l - 1)) * HS : nullptr;
        const __hip_bfloat16* Wih_l = wih + (size_t)l * 1536 * 512;
        const __hip_bfloat16* Whh_l = whh + (size_t)l * 1536 * 512;
        int njobs = l ? 12 : 6;
        for (int j = w; j < njobs; j += 8) {
            int src, rem;
            if (l) { src = j / 6; rem = j % 6; } else { src = 1; rem = j; }
            int gate = rem >> 1, rh = rem & 1;
            const __hip_bfloat16* A = (src ? hown : xin) + (size_t)(rh * 32) * 512;
            const __hip_bfloat16* W = (src ? Whh_l : Wih_l) + (size_t)(gate * 512 + c0) * 512;
            f32x4 acc[2] = {};
            wtile(A, W, 16, acc);
            store_parts(j, acc);
        }
        __syncthreads();
        const float* bih_l = bih + l * 1536;
        const float* bhh_l = bhh + l * 1536;
#pragma unroll
        for (int e = tid; e < 1024; e += 512) {
            int row = e >> 4, col16 = e & 15, col = c0 + col16;
            int rh = row >> 5, lr = row & 31;
            float gi[3], gh[3];
#pragma unroll
            for (int g = 0; g < 3; ++g) {
                if (l) {
                    gi[g] = parts[g * 2 + rh][lr][col16];
                    gh[g] = parts[6 + g * 2 + rh][lr][col16];
                } else {
                    gh[g] = parts[g * 2 + rh][lr][col16];
                    gi[g] = GI0[(size_t)(t * 64 + row) * 1536 + g * 512 + col];
                }
            }
            float rr = sigmf(gi[0] + gh[0] + bih_l[col] + bhh_l[col]);
            float zz = sigmf(gi[1] + gh[1] + bih_l[512 + col] + bhh_l[512 + col]);
            float nn = tanhf(gi[2] + bih_l[1024 + col] + rr * (gh[2] + bhh_l[1024 + col]));
            size_t ho = (size_t)(cur * 3 + l) * HS + (size_t)row * 512 + col;
            size_t hn = (size_t)(nxt * 3 + l) * HS + (size_t)row * 512 + col;
            float hnew = (1.f - zz) * nn + zz * hf[ho];
            hf[hn] = hnew;
            hb[hn] = __float2bfloat16(hnew);
        }
        __syncthreads();
    };

    // 64x512, K=512 projection with K-split-4: 8 wave jobs, LDS reduce, write out
    auto proj_stage = [&](const __hip_bfloat16* Ab, const __hip_bfloat16* Wb,
                          const float* bias, float* outf, __hip_bfloat16* outb,
                          int rowmul, int rowoff) {
        {
            int rh = w & 1, ks = w >> 1;
            const __hip_bfloat16* A = Ab + (size_t)(rh * 32) * 512 + ks * 128;
            const __hip_bfloat16* W = Wb + (size_t)c0 * 512 + ks * 128;
            f32x4 acc[2] = {};
            wtile(A, W, 4, acc);
            store_parts(w, acc);
        }
        __syncthreads();
#pragma unroll
        for (int e = tid; e < 1024; e += 512) {
            int row = e >> 4, col16 = e & 15, col = c0 + col16;
            int rh = row >> 5, lr = row & 31;
            float s = bias[col];
#pragma unroll
            for (int ks = 0; ks < 4; ++ks) s += parts[ks * 2 + rh][lr][col16];
            size_t off = (size_t)(row * rowmul + rowoff) * 512 + col;
            if (outf) outf[off] = s;
            else      outb[off] = __float2bfloat16(s);
        }
        __syncthreads();
    };

    auto attn_stage = [&]() {
        int gw = blk * 8 + w;  // 0..255; 512 (b,head) pairs -> 2 rounds
#pragma unroll 1
        for (int p = gw; p < 512; p += 256) {
            int b = p >> 3, nh = p & 7;
            const float* qrow = qbuf + (size_t)b * 512 + nh * 64;
            const float* kr = KV + (size_t)(b * 64 + lane) * 1024 + nh * 64;
            float sc = 0.f;
#pragma unroll
            for (int d = 0; d < 64; ++d) sc += qrow[d] * kr[d];
            sc *= 0.125f;  // 1/sqrt(64)
            float m = sc;
            for (int off = 32; off; off >>= 1) m = fmaxf(m, __shfl_xor(m, off, 64));
            float e = __expf(sc - m);
            float s = e;
            for (int off = 32; off; off >>= 1) s += __shfl_xor(s, off, 64);
            float pv = e / s;  // lane = kv position
            const float* vb = KV + (size_t)(b * 64) * 1024 + 512 + nh * 64 + lane;  // lane = d
            float acc = 0.f;
#pragma unroll
            for (int si = 0; si < 64; ++si)
                acc += __shfl(pv, si, 64) * vb[(size_t)si * 1024];
            ctxb[(size_t)b * 512 + nh * 64 + lane] = __float2bfloat16(acc);
        }
    };

#pragma unroll 1
    for (int t = 0; t < TT; ++t) {
        int cur = t & 1, nxt = cur ^ 1;
        gru_stage(0, t, cur); gridbar();
        gru_stage(1, t, cur); gridbar();
        gru_stage(2, t, cur); gridbar();
        proj_stage(hb + (size_t)(nxt * 3 + 2) * HS, wq, bq, qbuf, nullptr, 1, 0); gridbar();
        attn_stage(); gridbar();
        proj_stage(ctxb, wo, bo, nullptr, AO, TT, t);
        // no trailing barrier: next step's stage-1 touches no buffer AO-stage reads,
        // and qbuf/ctxb WARs are covered by the >=2 intervening barriers.
    }
}

// ---------------- host ----------------

extern "C" void kernel_launch(void* const* d_in, const int* in_sizes, int n_in,
                              void* d_out, int out_size, void* d_ws, size_t ws_size,
                              hipStream_t stream) {
    const float* enc        = (const float*)d_in[0];
    const int*   cap        = (const int*)d_in[1];
    const float* emb_tab    = (const float*)d_in[2];
    const float* w_ih       = (const float*)d_in[3];
    const float* w_hh       = (const float*)d_in[4];
    const float* b_ih       = (const float*)d_in[5];
    const float* b_hh       = (const float*)d_in[6];
    const float* in_proj_w  = (const float*)d_in[7];
    const float* in_proj_b  = (const float*)d_in[8];
    const float* out_proj_w = (const float*)d_in[9];
    const float* out_proj_b = (const float*)d_in[10];
    const float* fc_w       = (const float*)d_in[11];
    const float* fc_b       = (const float*)d_in[12];
    float* out = (float*)d_out;

    char* p = (char*)d_ws;
    auto alloc = [&](size_t bytes) {
        char* r = p;
        p += (bytes + 255) & ~(size_t)255;
        return r;
    };
    __hip_bfloat16* fcw_bf  = (__hip_bfloat16*)alloc((size_t)VV * HH * 2);
    __hip_bfloat16* enc_bf  = (__hip_bfloat16*)alloc((size_t)BB * SS * HH * 2);
    __hip_bfloat16* inp_bf  = (__hip_bfloat16*)alloc((size_t)1536 * 512 * 2);
    __hip_bfloat16* wih_bf  = (__hip_bfloat16*)alloc((size_t)3 * 1536 * 512 * 2);
    __hip_bfloat16* whh_bf  = (__hip_bfloat16*)alloc((size_t)3 * 1536 * 512 * 2);
    __hip_bfloat16* wo_bf   = (__hip_bfloat16*)alloc((size_t)512 * 512 * 2);
    __hip_bfloat16* xemb_bf = (__hip_bfloat16*)alloc((size_t)TT * BB * EE * 2);
    float* KV   = (float*)alloc((size_t)4096 * 1024 * 4);
    float* GI0  = (float*)alloc((size_t)1280 * 1536 * 4);
    float* hf   = (float*)alloc((size_t)2 * 3 * 64 * 512 * 4);
    __hip_bfloat16* hb = (__hip_bfloat16*)alloc((size_t)2 * 3 * 64 * 512 * 2);
    float* qbuf = (float*)alloc((size_t)64 * 512 * 4);
    __hip_bfloat16* ctxb = (__hip_bfloat16*)alloc((size_t)64 * 512 * 2);
    __hip_bfloat16* AO   = (__hip_bfloat16*)alloc((size_t)1280 * 512 * 2);
    int* bar = (int*)alloc(256);

    auto cvt = [&](const float* src, __hip_bfloat16* dst, int n) {
        f2bf_kernel<<<(n + 255) / 256, 256, 0, stream>>>(src, dst, n);
    };
    cvt(fc_w, fcw_bf, VV * HH);
    cvt(enc, enc_bf, BB * SS * HH);
    cvt(in_proj_w, inp_bf, 1536 * 512);
    cvt(w_ih, wih_bf, 3 * 1536 * 512);
    cvt(w_hh, whh_bf, 3 * 1536 * 512);
    cvt(out_proj_w, wo_bf, 512 * 512);
    gather_emb_kernel<<<(TT * BB * EE) / 256, 256, 0, stream>>>(emb_tab, cap, xemb_bf);
    init_kernel<<<(3 * 64 * 512) / 256, 256, 0, stream>>>(hf, hb, bar);

    // KV = enc @ [Wk;Wv]^T + [bk;bv]   (4096 x 1024, K=512)
    gemm128_kernel<<<dim3(32, 8), 256, 0, stream>>>(
        enc_bf, inp_bf + 512 * 512, in_proj_b + 512, KV, 512, 1024);

    // GI0 = xemb @ Wih0^T   (1280 x 1536, no bias)
    gemm128_kernel<<<dim3(10, 12), 256, 0, stream>>>(
        xemb_bf, wih_bf, nullptr, GI0, 512, 1536);

    // whole recurrence in one persistent kernel
    recurrence_kernel<<<NBLK, 512, 0, stream>>>(
        GI0, wih_bf, whh_bf, b_ih, b_hh,
        inp_bf, in_proj_b, wo_bf, out_proj_b,
        KV, hf, hb, qbuf, ctxb, AO, bar);

    // logits = AO @ fc_w^T + fc_b   (1280 x 32000) -> d_out (B,T,V)
    gemm128_kernel<<<dim3(10, 250), 256, 0, stream>>>(
        AO, fcw_bf, fc_b, out, 512, VV);
}